// Round 3
// baseline (179.108 us; speedup 1.0000x reference)
//
#include <hip/hip_runtime.h>
#include <hip/hip_bf16.h>
#include <stdint.h>

typedef __hip_bfloat16 bf16;
using f32x4 = __attribute__((ext_vector_type(4))) float;
using s16x8 = __attribute__((ext_vector_type(8))) short;

typedef __attribute__((address_space(1))) unsigned int gu32;
typedef __attribute__((address_space(3))) unsigned int lu32;

__device__ __forceinline__ void gll16(const void* g, void* l) {
  __builtin_amdgcn_global_load_lds((const gu32*)g, (lu32*)l, 16, 0, 0);
}

// ---------------- convert f32 -> bf16 ----------------
struct ConvJob { const float* src; bf16* dst; int n4; int pad; };
struct ConvParams { ConvJob j[10]; };
struct alignas(8) Bf4 { bf16 v[4]; };

__global__ void convert_kernel(ConvParams p) {
  ConvJob jb = p.j[blockIdx.z];
  int stride = gridDim.x * blockDim.x;
  for (int i = blockIdx.x * blockDim.x + threadIdx.x; i < jb.n4; i += stride) {
    float4 v = ((const float4*)jb.src)[i];
    Bf4 o;
    o.v[0] = __float2bfloat16(v.x);
    o.v[1] = __float2bfloat16(v.y);
    o.v[2] = __float2bfloat16(v.z);
    o.v[3] = __float2bfloat16(v.w);
    ((Bf4*)jb.dst)[i] = o;
  }
}

// ---------------- GEMM: C = A(MxK) @ W(NxK)^T + bias ----------------
// 256x256 tile, 512 threads = 8 waves as 2M x 4N; wave tile 128x64
// (mi 0..7, nj 0..3).  K = 512 = 8 K-tiles of BK=64; 4 phases per K-tile,
// each exactly 16 MFMA (m201 geometry):
//   p1: ks0 x mi0-3 (reads A[k0] mi0-3 + B[k0] nj0-3 = 8 ds_read)
//   p2: ks0 x mi4-7 (reads A[k0] mi4-7 = 4)
//   p3: ks1 x mi0-3 (reads A[k1] mi0-3 + B[k1] = 8)
//   p4: ks1 x mi4-7 (4)
// LDS: 2 buffers x {A,B} x 2 K-half pieces [256 rows x 32 cols] = 128 KiB,
// XOR-swizzled (chunk ^ (row&3) within 64 B rows; rule 21: linear gll16
// dest + inverse-swizzled global source + swizzled ds_read).
// Staging: 1 K-half piece (2 gll16/thread) per phase.  A piece may only be
// overwritten after its last reader's lgkmcnt(0)+barrier:
//   B[k0](u) drains @p1, A[k0](u) @p2, B[k1](u) @p3, A[k1](u) @p4 =>
//   p1: SA(u+1,k1) [other buffer]  p2: SB(u+2,k0)  p3: SA(u+2,k0)
//   p4: SB(u+2,k1)
// Counted waits (exact per-wave FIFO; never 0 mid-loop):
//   p2-end: vmcnt(6)  -> A(u,k1) landed (needed p3)
//   p4-end: vmcnt(8)  -> T(u+1) {B k0, A k0} + B(u+1,k1) landed
struct GemmSlice {
  const bf16* A; const bf16* W; const float* bias;
  bf16* dstQ; float* dstF;
  long lda; int dhalf; float scale; int mode;
};
struct GemmParams { GemmSlice s[6]; };

#define STG_A(v, h) do { \
    const bf16* s_ = Ab + (v) * 64 + (h) * 32; \
    bf16* d_ = lds + (((v) & 1) << 14) + (h) * 8192 + tid * 8; \
    gll16(s_, d_); gll16(s_ + (lda << 7), d_ + 4096); \
  } while (0)

#define STG_B(v, h) do { \
    const bf16* s_ = Wb + (v) * 64 + (h) * 32; \
    bf16* d_ = lds + 32768 + (((v) & 1) << 14) + (h) * 8192 + tid * 8; \
    gll16(s_, d_); gll16(s_ + (512 << 7), d_ + 4096); \
  } while (0)

#define GP(MB, H, RDB, STAGE_STMT, WAIT_STMT) do { \
    if (RDB) { \
      _Pragma("unroll") \
      for (int nj_ = 0; nj_ < 4; ++nj_) \
        bfr[nj_] = *(const s16x8*)(bB + (H) * 8192 + brow32 + nj_ * 512 + cw); \
    } \
    s16x8 af[4]; \
    _Pragma("unroll") \
    for (int i_ = 0; i_ < 4; ++i_) \
      af[i_] = *(const s16x8*)(bA + (H) * 8192 + arow32 + ((MB) + i_) * 512 + cw); \
    STAGE_STMT; \
    __builtin_amdgcn_s_barrier(); \
    asm volatile("s_waitcnt lgkmcnt(0)" ::: "memory"); \
    __builtin_amdgcn_sched_barrier(0); \
    __builtin_amdgcn_s_setprio(1); \
    _Pragma("unroll") \
    for (int i_ = 0; i_ < 4; ++i_) \
      _Pragma("unroll") \
      for (int nj_ = 0; nj_ < 4; ++nj_) \
        acc[(MB) + i_][nj_] = __builtin_amdgcn_mfma_f32_16x16x32_bf16(af[i_], bfr[nj_], acc[(MB) + i_][nj_], 0, 0, 0); \
    __builtin_amdgcn_s_setprio(0); \
    WAIT_STMT; \
    __builtin_amdgcn_s_barrier(); \
  } while (0)

__global__ __launch_bounds__(512, 2) void gemm_kernel(GemmParams p) {
  __shared__ alignas(16) bf16 lds[65536];   // 128 KiB: A buf0/1 @0/16384; B @32768/49152
  const GemmSlice sl = p.s[blockIdx.z];
  const long lda = sl.lda;
  const int tid = threadIdx.x;
  const int w = tid >> 6, ln = tid & 63;
  const int fr = ln & 15, fq = ln >> 4;
  const int wm = w >> 2, wn = w & 3;            // 2M x 4N wave grid
  const int gm0 = blockIdx.x * 256;
  const int gn0 = blockIdx.y * 256;
  // staging coords: piece [256 rows][32 cols]; thread covers rows r0, r0+128
  const int r0 = tid >> 2;
  const int c0 = ((tid & 3) ^ (r0 & 3)) * 8;    // inverse-swizzled source chunk
  const bf16* const Ab = sl.A + (long)(gm0 + r0) * lda + c0;
  const bf16* const Wb = sl.W + (long)(gn0 + r0) * 512 + c0;
  // fragment-read constants
  const int cw = (fq ^ (fr & 3)) * 8;           // swizzled chunk for frag reads
  const int arow32 = (wm * 128 + fr) * 32;
  const int brow32 = (wn * 64 + fr) * 32;

  f32x4 acc[8][4] = {};

  // prologue: T0 all 4 pieces + T1 {Bk0, Ak0, Bk1}; A(1,k1) staged at u=0 p1
  STG_B(0, 0); STG_A(0, 0); STG_B(0, 1); STG_A(0, 1);
  __builtin_amdgcn_sched_barrier(0);
  STG_B(1, 0); STG_A(1, 0); STG_B(1, 1);
  asm volatile("s_waitcnt vmcnt(8)" ::: "memory");   // T0 {Bk0,Ak0,Bk1} landed
  __builtin_amdgcn_sched_barrier(0);
  __builtin_amdgcn_s_barrier();

#pragma unroll
  for (int u = 0; u < 8; ++u) {
    const bf16* bA = lds + ((u & 1) << 14);
    const bf16* bB = lds + 32768 + ((u & 1) << 14);
    s16x8 bfr[4];
    // p1: ks0 mi0-3, read B[k0]; stage A(u+1,k1) into other buffer
    GP(0, 0, 1, { if (u <= 6) STG_A(u + 1, 1); }, {});
    // p2: ks0 mi4-7; stage B(u+2,k0); wait A(u,k1)
    GP(4, 0, 0, { if (u <= 5) STG_B(u + 2, 0); },
       { if (u <= 6) { asm volatile("s_waitcnt vmcnt(6)" ::: "memory"); }
         else        { asm volatile("s_waitcnt vmcnt(0)" ::: "memory"); }
         __builtin_amdgcn_sched_barrier(0); });
    // p3: ks1 mi0-3, read B[k1]; stage A(u+2,k0)
    GP(0, 1, 1, { if (u <= 5) STG_A(u + 2, 0); }, {});
    // p4: ks1 mi4-7; stage B(u+2,k1); wait T(u+1) pieces
    GP(4, 1, 0, { if (u <= 5) STG_B(u + 2, 1); },
       { if (u <= 5)      { asm volatile("s_waitcnt vmcnt(8)" ::: "memory"); __builtin_amdgcn_sched_barrier(0); }
         else if (u == 6) { asm volatile("s_waitcnt vmcnt(2)" ::: "memory"); __builtin_amdgcn_sched_barrier(0); } });
  }

  // epilogue: row = gm0 + wm*128 + mi*16 + fq*4 + r ; col = gn0 + wn*64 + nj*16 + fr
  if (sl.mode == 0) {
#pragma unroll
    for (int mi = 0; mi < 8; ++mi)
#pragma unroll
      for (int nj = 0; nj < 4; ++nj) {
        const int col = gn0 + wn * 64 + nj * 16 + fr;
        const int h = col >> 6;
        const int dd = (col & 63) + sl.dhalf;
        const float bia = sl.bias[col];
#pragma unroll
        for (int r = 0; r < 4; ++r) {
          const int row = gm0 + wm * 128 + mi * 16 + fq * 4 + r;
          const int b = row >> 9, t = row & 511;
          const float v = (acc[mi][nj][r] + bia) * sl.scale;
          sl.dstQ[(((long)(b * 8 + h) * 512 + t) << 7) + dd] = __float2bfloat16(v);
        }
      }
  } else if (sl.mode == 2) {
#pragma unroll
    for (int mi = 0; mi < 8; ++mi)
#pragma unroll
      for (int nj = 0; nj < 4; ++nj) {
        const int col = gn0 + wn * 64 + nj * 16 + fr;
        const int h = col >> 6;
        const int dd = (col & 63) + sl.dhalf;
        const float bia = sl.bias[col];
        const int row0 = gm0 + wm * 128 + mi * 16 + fq * 4;
        const int b = row0 >> 9, t = row0 & 511;
        Bf4 o;
#pragma unroll
        for (int r = 0; r < 4; ++r) o.v[r] = __float2bfloat16(acc[mi][nj][r] + bia);
        *(Bf4*)(sl.dstQ + (((long)(b * 8 + h) * 128 + dd) << 9) + t) = o;
      }
  } else {
#pragma unroll
    for (int mi = 0; mi < 8; ++mi)
#pragma unroll
      for (int nj = 0; nj < 4; ++nj) {
        const int col = gn0 + wn * 64 + nj * 16 + fr;
        const float bia = sl.bias[col];
#pragma unroll
        for (int r = 0; r < 4; ++r) {
          const int row = gm0 + wm * 128 + mi * 16 + fq * 4 + r;
          sl.dstF[(long)row * 512 + col] = acc[mi][nj][r] + bia;
        }
      }
  }
}

// ---------------- flash attention ----------------
// grid: 1024 blocks = 256 bh x 4 q-tiles of 128 rows (XCD-chunk swizzled).
// 256 threads = 4 waves x 32 q-rows (mi=2). KVBLK=64, 8 k-tiles, dbuf via
// global_load_lds + counted vmcnt. All LDS tiles XOR-swizzled (T2, rule 21):
// linear gll16 dest + inverse-swizzled global source + swizzled ds_read.
// Q pre-scaled by log2e/8; no running max (scores bounded ~|3|).
#define STAGE(kt, bK, bV) do { \
    _Pragma("unroll") \
    for (int p_ = 0; p_ < 4; ++p_) \
      gll16(kgb + (kt) * 8192 + p_ * 2048, (bK) + tid * 8 + p_ * 2048); \
    _Pragma("unroll") \
    for (int p_ = 0; p_ < 4; ++p_) \
      gll16(vgb + (kt) * 64 + p_ * 16384, (bV) + tid * 8 + p_ * 2048); \
  } while (0)

#define COMPUTE(bK, bV) do { \
  f32x4 s2[2][4] = {}; \
  _Pragma("unroll") \
  for (int ks = 0; ks < 4; ++ks) { \
    _Pragma("unroll") \
    for (int ni = 0; ni < 4; ++ni) { \
      const int row_ = ni * 16 + fr; \
      const s16x8 kf = *(const s16x8*)((bK) + row_ * 128 + ((ks * 32 + fq * 8) ^ ((row_ & 7) << 3))); \
      _Pragma("unroll") \
      for (int mi = 0; mi < 2; ++mi) \
        s2[mi][ni] = __builtin_amdgcn_mfma_f32_16x16x32_bf16(qf[mi][ks], kf, s2[mi][ni], 0, 0, 0); \
    } \
  } \
  _Pragma("unroll") \
  for (int mi = 0; mi < 2; ++mi) \
    _Pragma("unroll") \
    for (int r = 0; r < 4; ++r) { \
      float ps = 0.f; \
      _Pragma("unroll") \
      for (int ni = 0; ni < 4; ++ni) { \
        const float pe = __builtin_amdgcn_exp2f(s2[mi][ni][r]); \
        s2[mi][ni][r] = pe; ps += pe; \
      } \
      ps += __shfl_xor(ps, 1); ps += __shfl_xor(ps, 2); \
      ps += __shfl_xor(ps, 4); ps += __shfl_xor(ps, 8); \
      lrow[mi][r] += ps; \
    } \
  _Pragma("unroll") \
  for (int mi = 0; mi < 2; ++mi) \
    _Pragma("unroll") \
    for (int ni = 0; ni < 4; ++ni) \
      _Pragma("unroll") \
      for (int r = 0; r < 4; ++r) { \
        const int rp = mi * 16 + fq * 4 + r; \
        sPw[rp * 64 + ((ni * 16 + fr) ^ ((rp & 7) << 3))] = __float2bfloat16(s2[mi][ni][r]); \
      } \
  _Pragma("unroll") \
  for (int ks = 0; ks < 2; ++ks) { \
    s16x8 pf[2]; \
    _Pragma("unroll") \
    for (int mi = 0; mi < 2; ++mi) { \
      const int row_ = mi * 16 + fr; \
      pf[mi] = *(const s16x8*)(sPw + row_ * 64 + ((ks * 32 + fq * 8) ^ ((row_ & 7) << 3))); \
    } \
    _Pragma("unroll") \
    for (int nj = 0; nj < 8; ++nj) { \
      const int row_ = nj * 16 + fr; \
      const s16x8 vf = *(const s16x8*)((bV) + row_ * 64 + ((ks * 32 + fq * 8) ^ ((row_ & 7) << 3))); \
      _Pragma("unroll") \
      for (int mi = 0; mi < 2; ++mi) \
        o[mi][nj] = __builtin_amdgcn_mfma_f32_16x16x32_bf16(pf[mi], vf, o[mi][nj], 0, 0, 0); \
    } \
  } \
} while (0)

__global__ __launch_bounds__(256, 2) void attn_kernel(const bf16* __restrict__ Q,
                                                      const bf16* __restrict__ K,
                                                      const bf16* __restrict__ Vt,
                                                      bf16* __restrict__ AO) {
  __shared__ alignas(16) bf16 lds[40960];   // 80 KiB exactly -> 2 blocks/CU
  bf16* const ldsK0 = lds;                  // [64][128]
  bf16* const ldsV0 = lds + 8192;           // [128][64]
  bf16* const ldsK1 = lds + 16384;
  bf16* const ldsV1 = lds + 24576;
  bf16* const sP    = lds + 32768;          // 4 waves x [32][64]
  const int tid = threadIdx.x;
  const int w = tid >> 6, ln = tid & 63;
  const int fr = ln & 15, fq = ln >> 4;
  const int lg = (blockIdx.x & 7) * 128 + (blockIdx.x >> 3);
  const int bh = lg >> 2;
  const int q0 = (lg & 3) * 128;
  const long base = (long)bh << 16;         // bh * 512 * 128
  bf16* const sPw = sP + w * 2048;

  // thread-constant staging source bases (inverse-swizzled global addresses)
  const int kr0 = tid >> 4, kc = tid & 15;          // K/Q chunk coords
  const int vr0 = tid >> 3, vc = tid & 7;           // V^T chunk coords
  const bf16* const kgb = K + base + kr0 * 128 + ((kc ^ (kr0 & 7)) * 8);
  const bf16* const vgb = Vt + base + (long)vr0 * 512 + ((vc ^ (vr0 & 7)) * 8);

  // --- stage Q tile (128x128) swizzled into lds[0..16383], read fragments
  {
    const bf16* const qgb = Q + base + (long)q0 * 128 + kr0 * 128 + ((kc ^ (kr0 & 7)) * 8);
#pragma unroll
    for (int p = 0; p < 8; ++p)
      gll16(qgb + p * 2048, lds + tid * 8 + p * 2048);
  }
  __syncthreads();   // drains vmcnt(0): Q landed for all waves
  s16x8 qf[2][4];
#pragma unroll
  for (int mi = 0; mi < 2; ++mi) {
    const int row = w * 32 + mi * 16 + fr;
#pragma unroll
    for (int ks = 0; ks < 4; ++ks)
      qf[mi][ks] = *(const s16x8*)(lds + row * 128 + ((ks * 32 + fq * 8) ^ ((row & 7) << 3)));
  }
  __syncthreads();   // drains lgkm: Q region free for tile0

  f32x4 o[2][8] = {};
  float lrow[2][4] = {};

  STAGE(0, ldsK0, ldsV0);
  STAGE(1, ldsK1, ldsV1);

  for (int kt = 0; kt < 7; ++kt) {
    const bf16* bK = (kt & 1) ? ldsK1 : ldsK0;
    const bf16* bV = (kt & 1) ? ldsV1 : ldsV0;
    asm volatile("s_waitcnt vmcnt(8)" ::: "memory");   // tile kt landed; kt+1 in flight
    __builtin_amdgcn_sched_barrier(0);
    __builtin_amdgcn_s_barrier();
    COMPUTE(bK, bV);
    asm volatile("s_waitcnt lgkmcnt(0)" ::: "memory"); // my LDS reads complete
    __builtin_amdgcn_sched_barrier(0);
    __builtin_amdgcn_s_barrier();                      // everyone done reading buf
    if (kt < 6) STAGE(kt + 2, (bf16*)bK, (bf16*)bV);   // overwrite current buf
  }
  asm volatile("s_waitcnt vmcnt(0)" ::: "memory");
  __builtin_amdgcn_sched_barrier(0);
  __builtin_amdgcn_s_barrier();
  COMPUTE(ldsK1, ldsV1);   // kt = 7

  // epilogue: O /= l, write AO[b][t][h*128 + d]
  const int b = bh >> 3, h = bh & 7;
  float rl[2][4];
#pragma unroll
  for (int mi = 0; mi < 2; ++mi)
#pragma unroll
    for (int r = 0; r < 4; ++r) rl[mi][r] = 1.f / lrow[mi][r];
#pragma unroll
  for (int mi = 0; mi < 2; ++mi)
#pragma unroll
    for (int nj = 0; nj < 8; ++nj) {
      const int col = h * 128 + nj * 16 + fr;
#pragma unroll
      for (int r = 0; r < 4; ++r) {
        const int trow = q0 + w * 32 + mi * 16 + fq * 4 + r;
        AO[((long)(b * 512 + trow) << 10) + col] = __float2bfloat16(o[mi][nj][r] * rl[mi][r]);
      }
    }
}

// ---------------- launch ----------------
extern "C" void kernel_launch(void* const* d_in, const int* in_sizes, int n_in,
                              void* d_out, int out_size, void* d_ws, size_t ws_size,
                              hipStream_t stream) {
  const float* xf = (const float*)d_in[0];
  const float* xs = (const float*)d_in[1];
  // weight order in WW: 0=wq1,1=wk1,2=wv1,3=wq2,4=wk2,5=wv2,6=wo1,7=wo2
  const float* w_f[8] = { (const float*)d_in[2], (const float*)d_in[4], (const float*)d_in[6],
                          (const float*)d_in[8], (const float*)d_in[10], (const float*)d_in[12],
                          (const float*)d_in[14], (const float*)d_in[16] };

  bf16* ws = (bf16*)d_ws;
  bf16* XF = ws;                       // 8,388,608 bf16
  bf16* XS = ws + 8388608;             // 8,388,608
  bf16* WW = ws + 16777216;            // 8 x 262,144
  bf16* Qb = ws + 18874368;            // 16,777,216 each
  bf16* Kb = Qb + 16777216;
  bf16* Vb = Kb + 16777216;            // V^T layout (bh, d, t)
  bf16* AO = ws;                       // reuse XF+XS region

  ConvParams cp;
  cp.j[0] = { xf, XF, 2097152, 0 };
  cp.j[1] = { xs, XS, 2097152, 0 };
  for (int i = 0; i < 8; ++i) cp.j[2 + i] = { w_f[i], WW + i * 262144, 65536, 0 };
  convert_kernel<<<dim3(512, 1, 10), 256, 0, stream>>>(cp);

  const float qsc = 0.125f * 1.44269504088896f;   // fold log2(e) so attn uses exp2
  GemmParams gp;
  gp.s[0] = { XF, WW + 0 * 262144, (const float*)d_in[3],  Qb, nullptr, 512, 0,  qsc, 0 };
  gp.s[1] = { XS, WW + 3 * 262144, (const float*)d_in[9],  Qb, nullptr, 512, 64, qsc, 0 };
  gp.s[2] = { XF, WW + 1 * 262144, (const float*)d_in[5],  Kb, nullptr, 512, 0,  1.f, 0 };
  gp.s[3] = { XS, WW + 4 * 262144, (const float*)d_in[11], Kb, nullptr, 512, 64, 1.f, 0 };
  gp.s[4] = { XF, WW + 2 * 262144, (const float*)d_in[7],  Vb, nullptr, 512, 0,  1.f, 2 };
  gp.s[5] = { XS, WW + 5 * 262144, (const float*)d_in[13], Vb, nullptr, 512, 64, 1.f, 2 };
  gemm_kernel<<<dim3(64, 2, 6), 512, 0, stream>>>(gp);

  attn_kernel<<<dim3(1024), 256, 0, stream>>>(Qb, Kb, Vb, AO);

  float* out = (float*)d_out;
  GemmParams op;
  op.s[0] = { AO,       WW + 6 * 262144, (const float*)d_in[15], nullptr, out,           1024, 0, 1.f, 1 };
  op.s[1] = { AO + 512, WW + 7 * 262144, (const float*)d_in[17], nullptr, out + 8388608, 1024, 0, 1.f, 1 };
  op.s[2] = op.s[0]; op.s[3] = op.s[0]; op.s[4] = op.s[0]; op.s[5] = op.s[0];
  gemm_kernel<<<dim3(64, 2, 2), 512, 0, stream>>>(op);
}

// Round 4
// 171.748 us; speedup vs baseline: 1.0429x; 1.0429x over previous
//
#include <hip/hip_runtime.h>
#include <hip/hip_bf16.h>
#include <stdint.h>

typedef __hip_bfloat16 bf16;
using f32x4 = __attribute__((ext_vector_type(4))) float;
using s16x8 = __attribute__((ext_vector_type(8))) short;

typedef __attribute__((address_space(1))) unsigned int gu32;
typedef __attribute__((address_space(3))) unsigned int lu32;

__device__ __forceinline__ void gll16(const void* g, void* l) {
  __builtin_amdgcn_global_load_lds((const gu32*)g, (lu32*)l, 16, 0, 0);
}

// ---------------- convert f32 -> bf16 ----------------
struct ConvJob { const float* src; bf16* dst; int n4; int pad; };
struct ConvParams { ConvJob j[10]; };
struct alignas(8) Bf4 { bf16 v[4]; };

__global__ void convert_kernel(ConvParams p) {
  ConvJob jb = p.j[blockIdx.z];
  int stride = gridDim.x * blockDim.x;
  for (int i = blockIdx.x * blockDim.x + threadIdx.x; i < jb.n4; i += stride) {
    float4 v = ((const float4*)jb.src)[i];
    Bf4 o;
    o.v[0] = __float2bfloat16(v.x);
    o.v[1] = __float2bfloat16(v.y);
    o.v[2] = __float2bfloat16(v.z);
    o.v[3] = __float2bfloat16(v.w);
    ((Bf4*)jb.dst)[i] = o;
  }
}

// ---------------- GEMM: C = A(MxK) @ W(NxK)^T + bias ----------------
// Faithful m201-template port. 256x256 tile, 512 threads = 8 waves (2M x 4N),
// wave tile 128x64 (mi 0..7, nj 0..3). K = 512 = 8 K-tiles of BK=64.
// 4 phases per K-tile, one C-quadrant (16 MFMA) each:
//   P1: read A mi0-3 (8 b128) + B nj0-1 (4) -> MM(mi0-3, nj0-1)
//   P2: read B nj2-3 (4)                    -> MM(mi0-3, nj2-3)  [A reused]
//   P3: read A mi4-7 (8)                    -> MM(mi4-7, nj0-1)  [B01 reused]
//   P4: (no reads)                          -> MM(mi4-7, nj2-3)  [reused]
// LDS 128 KiB: A bufs @0/16384, B bufs @32768/49152 (each [256][64] bf16,
// halves = rows 0-127 / 128-255, contiguous). XOR swizzle (rule 21): linear
// gll16 dest + inverse-swizzled global source chunk ((tid&7)^(row&7)) +
// swizzled ds_read col ((ks*32+fq*8) ^ ((fr&7)*8)).
// Staging: 1 half-tile (2 gll16/thread) per phase:
//   u.P1: Ah0(u+1)  u.P2: Ah1(u+1)  u.P3: Bh0(u+2)  u.P4: Bh1(u+2)
// Buffer safety (stage issued only after target half's last-reader barrier):
//   A halves of buf(u) last read u.P3 -> Ah(u+2) staged u+1.P1/P2 OK;
//   B halves of buf(u) last read u.P2 -> Bh(u+2) staged u.P3/P4 OK.
// Single counted wait per K-tile at P4: vmcnt(4) leaves {u.P3,u.P4} stages
// outstanding => everything through u.P2 (= tile u+1 complete) landed.
struct GemmSlice {
  const bf16* A; const bf16* W; const float* bias;
  bf16* dstQ; float* dstF;
  long lda; int dhalf; float scale; int mode;
};
struct GemmParams { GemmSlice s[6]; };

#define STG_A(kt, h) do { \
    const bf16* s_ = Ab + (long)((h) * 128) * lda + (kt) * 64; \
    bf16* d_ = lds + (((kt) & 1) << 14) + (h) * 8192 + tid * 8; \
    gll16(s_, d_); gll16(s_ + (lda << 6), d_ + 4096); \
  } while (0)

#define STG_B(kt, h) do { \
    const bf16* s_ = Wb + (long)((h) * 128) * 512 + (kt) * 64; \
    bf16* d_ = lds + 32768 + (((kt) & 1) << 14) + (h) * 8192 + tid * 8; \
    gll16(s_, d_); gll16(s_ + (512 << 6), d_ + 4096); \
  } while (0)

#define RD_A(MB) do { \
    _Pragma("unroll") \
    for (int i_ = 0; i_ < 4; ++i_) { \
      const bf16* rp_ = bA + (wm * 128 + ((MB) + i_) * 16 + fr) * 64; \
      aF[i_][0] = *(const s16x8*)(rp_ + cw0); \
      aF[i_][1] = *(const s16x8*)(rp_ + cw1); \
    } \
  } while (0)

#define RD_B(NB, DST) do { \
    _Pragma("unroll") \
    for (int j_ = 0; j_ < 2; ++j_) { \
      const bf16* rp_ = bB + (wn * 64 + ((NB) + j_) * 16 + fr) * 64; \
      DST[j_][0] = *(const s16x8*)(rp_ + cw0); \
      DST[j_][1] = *(const s16x8*)(rp_ + cw1); \
    } \
  } while (0)

#define MM(MB, NB, BF) do { \
    __builtin_amdgcn_s_setprio(1); \
    _Pragma("unroll") \
    for (int i_ = 0; i_ < 4; ++i_) \
      _Pragma("unroll") \
      for (int j_ = 0; j_ < 2; ++j_) { \
        acc[(MB) + i_][(NB) + j_] = __builtin_amdgcn_mfma_f32_16x16x32_bf16(aF[i_][0], BF[j_][0], acc[(MB) + i_][(NB) + j_], 0, 0, 0); \
        acc[(MB) + i_][(NB) + j_] = __builtin_amdgcn_mfma_f32_16x16x32_bf16(aF[i_][1], BF[j_][1], acc[(MB) + i_][(NB) + j_], 0, 0, 0); \
      } \
    __builtin_amdgcn_s_setprio(0); \
  } while (0)

#define BAR __builtin_amdgcn_s_barrier()
#define LGKM0 do { asm volatile("s_waitcnt lgkmcnt(0)" ::: "memory"); \
                   __builtin_amdgcn_sched_barrier(0); } while (0)

__global__ __launch_bounds__(512, 2) void gemm_kernel(GemmParams p) {
  __shared__ alignas(16) bf16 lds[65536];   // 128 KiB
  const GemmSlice sl = p.s[blockIdx.z];
  const long lda = sl.lda;
  const int tid = threadIdx.x;
  const int w = tid >> 6, ln = tid & 63;
  const int fr = ln & 15, fq = ln >> 4;
  const int wm = w >> 2, wn = w & 3;            // 2M x 4N wave grid
  const int gm0 = blockIdx.x * 256;
  const int gn0 = blockIdx.y * 256;
  // staging: half-tile [128][64]; thread covers chunks tid (row r0) and tid+512 (row r0+64)
  const int r0 = tid >> 3;
  const int c0 = ((tid & 7) ^ (r0 & 7)) * 8;    // inverse-swizzled source chunk
  const bf16* const Ab = sl.A + (long)(gm0 + r0) * lda + c0;
  const bf16* const Wb = sl.W + (long)(gn0 + r0) * 512 + c0;
  // swizzled frag-read cols (frag row & 7 == fr & 7 always)
  const int cw0 = (fq * 8) ^ ((fr & 7) * 8);
  const int cw1 = (32 + fq * 8) ^ ((fr & 7) * 8);

  f32x4 acc[8][4] = {};

  // prologue: T0 all 4 halves + T1 {Bh0, Bh1}; T1's A staged at u=0 P1/P2
  STG_A(0, 0); STG_A(0, 1); STG_B(0, 0); STG_B(0, 1);
  __builtin_amdgcn_sched_barrier(0);
  STG_B(1, 0); STG_B(1, 1);
  asm volatile("s_waitcnt vmcnt(4)" ::: "memory");   // T0 landed
  __builtin_amdgcn_sched_barrier(0);
  BAR;

#pragma unroll
  for (int u = 0; u < 8; ++u) {
    const bf16* bA = lds + ((u & 1) << 14);
    const bf16* bB = lds + 32768 + ((u & 1) << 14);
    s16x8 aF[4][2], b01[2][2], b23[2][2];
    // P1
    RD_A(0); RD_B(0, b01);
    if (u < 7) STG_A(u + 1, 0);
    BAR; LGKM0;
    MM(0, 0, b01);
    BAR;
    // P2
    RD_B(2, b23);
    if (u < 7) STG_A(u + 1, 1);
    BAR; LGKM0;
    MM(0, 2, b23);
    BAR;
    // P3
    RD_A(4);
    if (u < 6) STG_B(u + 2, 0);
    BAR; LGKM0;
    MM(4, 0, b01);
    BAR;
    // P4 (no reads); single per-K-tile vmcnt gate
    if (u < 6) STG_B(u + 2, 1);
    BAR; LGKM0;
    MM(4, 2, b23);
    if (u < 6)       { asm volatile("s_waitcnt vmcnt(4)" ::: "memory"); __builtin_amdgcn_sched_barrier(0); }
    else if (u == 6) { asm volatile("s_waitcnt vmcnt(0)" ::: "memory"); __builtin_amdgcn_sched_barrier(0); }
    BAR;
  }

  // epilogue: row = gm0 + wm*128 + mi*16 + fq*4 + r ; col = gn0 + wn*64 + nj*16 + fr
  if (sl.mode == 0) {
#pragma unroll
    for (int mi = 0; mi < 8; ++mi)
#pragma unroll
      for (int nj = 0; nj < 4; ++nj) {
        const int col = gn0 + wn * 64 + nj * 16 + fr;
        const int h = col >> 6;
        const int dd = (col & 63) + sl.dhalf;
        const float bia = sl.bias[col];
#pragma unroll
        for (int r = 0; r < 4; ++r) {
          const int row = gm0 + wm * 128 + mi * 16 + fq * 4 + r;
          const int b = row >> 9, t = row & 511;
          const float v = (acc[mi][nj][r] + bia) * sl.scale;
          sl.dstQ[(((long)(b * 8 + h) * 512 + t) << 7) + dd] = __float2bfloat16(v);
        }
      }
  } else if (sl.mode == 2) {
#pragma unroll
    for (int mi = 0; mi < 8; ++mi)
#pragma unroll
      for (int nj = 0; nj < 4; ++nj) {
        const int col = gn0 + wn * 64 + nj * 16 + fr;
        const int h = col >> 6;
        const int dd = (col & 63) + sl.dhalf;
        const float bia = sl.bias[col];
        const int row0 = gm0 + wm * 128 + mi * 16 + fq * 4;
        const int b = row0 >> 9, t = row0 & 511;
        Bf4 o;
#pragma unroll
        for (int r = 0; r < 4; ++r) o.v[r] = __float2bfloat16(acc[mi][nj][r] + bia);
        *(Bf4*)(sl.dstQ + (((long)(b * 8 + h) * 128 + dd) << 9) + t) = o;
      }
  } else {
#pragma unroll
    for (int mi = 0; mi < 8; ++mi)
#pragma unroll
      for (int nj = 0; nj < 4; ++nj) {
        const int col = gn0 + wn * 64 + nj * 16 + fr;
        const float bia = sl.bias[col];
#pragma unroll
        for (int r = 0; r < 4; ++r) {
          const int row = gm0 + wm * 128 + mi * 16 + fq * 4 + r;
          sl.dstF[(long)row * 512 + col] = acc[mi][nj][r] + bia;
        }
      }
  }
}

// ---------------- flash attention ----------------
// grid: 1024 blocks = 256 bh x 4 q-tiles of 128 rows (XCD-chunk swizzled).
// 256 threads = 4 waves x 32 q-rows (mi=2). KVBLK=64, 8 k-tiles, dbuf via
// global_load_lds + counted vmcnt. All LDS tiles XOR-swizzled (T2, rule 21):
// linear gll16 dest + inverse-swizzled global source + swizzled ds_read.
// Q pre-scaled by log2e/8; no running max (scores bounded ~|3|).
#define STAGE(kt, bK, bV) do { \
    _Pragma("unroll") \
    for (int p_ = 0; p_ < 4; ++p_) \
      gll16(kgb + (kt) * 8192 + p_ * 2048, (bK) + tid * 8 + p_ * 2048); \
    _Pragma("unroll") \
    for (int p_ = 0; p_ < 4; ++p_) \
      gll16(vgb + (kt) * 64 + p_ * 16384, (bV) + tid * 8 + p_ * 2048); \
  } while (0)

#define COMPUTE(bK, bV) do { \
  f32x4 s2[2][4] = {}; \
  _Pragma("unroll") \
  for (int ks = 0; ks < 4; ++ks) { \
    _Pragma("unroll") \
    for (int ni = 0; ni < 4; ++ni) { \
      const int row_ = ni * 16 + fr; \
      const s16x8 kf = *(const s16x8*)((bK) + row_ * 128 + ((ks * 32 + fq * 8) ^ ((row_ & 7) << 3))); \
      _Pragma("unroll") \
      for (int mi = 0; mi < 2; ++mi) \
        s2[mi][ni] = __builtin_amdgcn_mfma_f32_16x16x32_bf16(qf[mi][ks], kf, s2[mi][ni], 0, 0, 0); \
    } \
  } \
  _Pragma("unroll") \
  for (int mi = 0; mi < 2; ++mi) \
    _Pragma("unroll") \
    for (int r = 0; r < 4; ++r) { \
      float ps = 0.f; \
      _Pragma("unroll") \
      for (int ni = 0; ni < 4; ++ni) { \
        const float pe = __builtin_amdgcn_exp2f(s2[mi][ni][r]); \
        s2[mi][ni][r] = pe; ps += pe; \
      } \
      ps += __shfl_xor(ps, 1); ps += __shfl_xor(ps, 2); \
      ps += __shfl_xor(ps, 4); ps += __shfl_xor(ps, 8); \
      lrow[mi][r] += ps; \
    } \
  _Pragma("unroll") \
  for (int mi = 0; mi < 2; ++mi) \
    _Pragma("unroll") \
    for (int ni = 0; ni < 4; ++ni) \
      _Pragma("unroll") \
      for (int r = 0; r < 4; ++r) { \
        const int rp = mi * 16 + fq * 4 + r; \
        sPw[rp * 64 + ((ni * 16 + fr) ^ ((rp & 7) << 3))] = __float2bfloat16(s2[mi][ni][r]); \
      } \
  _Pragma("unroll") \
  for (int ks = 0; ks < 2; ++ks) { \
    s16x8 pf[2]; \
    _Pragma("unroll") \
    for (int mi = 0; mi < 2; ++mi) { \
      const int row_ = mi * 16 + fr; \
      pf[mi] = *(const s16x8*)(sPw + row_ * 64 + ((ks * 32 + fq * 8) ^ ((row_ & 7) << 3))); \
    } \
    _Pragma("unroll") \
    for (int nj = 0; nj < 8; ++nj) { \
      const int row_ = nj * 16 + fr; \
      const s16x8 vf = *(const s16x8*)((bV) + row_ * 64 + ((ks * 32 + fq * 8) ^ ((row_ & 7) << 3))); \
      _Pragma("unroll") \
      for (int mi = 0; mi < 2; ++mi) \
        o[mi][nj] = __builtin_amdgcn_mfma_f32_16x16x32_bf16(pf[mi], vf, o[mi][nj], 0, 0, 0); \
    } \
  } \
} while (0)

__global__ __launch_bounds__(256, 2) void attn_kernel(const bf16* __restrict__ Q,
                                                      const bf16* __restrict__ K,
                                                      const bf16* __restrict__ Vt,
                                                      bf16* __restrict__ AO) {
  __shared__ alignas(16) bf16 lds[40960];   // 80 KiB exactly -> 2 blocks/CU
  bf16* const ldsK0 = lds;                  // [64][128]
  bf16* const ldsV0 = lds + 8192;           // [128][64]
  bf16* const ldsK1 = lds + 16384;
  bf16* const ldsV1 = lds + 24576;
  bf16* const sP    = lds + 32768;          // 4 waves x [32][64]
  const int tid = threadIdx.x;
  const int w = tid >> 6, ln = tid & 63;
  const int fr = ln & 15, fq = ln >> 4;
  const int lg = (blockIdx.x & 7) * 128 + (blockIdx.x >> 3);
  const int bh = lg >> 2;
  const int q0 = (lg & 3) * 128;
  const long base = (long)bh << 16;         // bh * 512 * 128
  bf16* const sPw = sP + w * 2048;

  // thread-constant staging source bases (inverse-swizzled global addresses)
  const int kr0 = tid >> 4, kc = tid & 15;          // K/Q chunk coords
  const int vr0 = tid >> 3, vc = tid & 7;           // V^T chunk coords
  const bf16* const kgb = K + base + kr0 * 128 + ((kc ^ (kr0 & 7)) * 8);
  const bf16* const vgb = Vt + base + (long)vr0 * 512 + ((vc ^ (vr0 & 7)) * 8);

  // --- stage Q tile (128x128) swizzled into lds[0..16383], read fragments
  {
    const bf16* const qgb = Q + base + (long)q0 * 128 + kr0 * 128 + ((kc ^ (kr0 & 7)) * 8);
#pragma unroll
    for (int p = 0; p < 8; ++p)
      gll16(qgb + p * 2048, lds + tid * 8 + p * 2048);
  }
  __syncthreads();   // drains vmcnt(0): Q landed for all waves
  s16x8 qf[2][4];
#pragma unroll
  for (int mi = 0; mi < 2; ++mi) {
    const int row = w * 32 + mi * 16 + fr;
#pragma unroll
    for (int ks = 0; ks < 4; ++ks)
      qf[mi][ks] = *(const s16x8*)(lds + row * 128 + ((ks * 32 + fq * 8) ^ ((row & 7) << 3)));
  }
  __syncthreads();   // drains lgkm: Q region free for tile0

  f32x4 o[2][8] = {};
  float lrow[2][4] = {};

  STAGE(0, ldsK0, ldsV0);
  STAGE(1, ldsK1, ldsV1);

  for (int kt = 0; kt < 7; ++kt) {
    const bf16* bK = (kt & 1) ? ldsK1 : ldsK0;
    const bf16* bV = (kt & 1) ? ldsV1 : ldsV0;
    asm volatile("s_waitcnt vmcnt(8)" ::: "memory");   // tile kt landed; kt+1 in flight
    __builtin_amdgcn_sched_barrier(0);
    __builtin_amdgcn_s_barrier();
    COMPUTE(bK, bV);
    asm volatile("s_waitcnt lgkmcnt(0)" ::: "memory"); // my LDS reads complete
    __builtin_amdgcn_sched_barrier(0);
    __builtin_amdgcn_s_barrier();                      // everyone done reading buf
    if (kt < 6) STAGE(kt + 2, (bf16*)bK, (bf16*)bV);   // overwrite current buf
  }
  asm volatile("s_waitcnt vmcnt(0)" ::: "memory");
  __builtin_amdgcn_sched_barrier(0);
  __builtin_amdgcn_s_barrier();
  COMPUTE(ldsK1, ldsV1);   // kt = 7

  // epilogue: O /= l, write AO[b][t][h*128 + d]
  const int b = bh >> 3, h = bh & 7;
  float rl[2][4];
#pragma unroll
  for (int mi = 0; mi < 2; ++mi)
#pragma unroll
    for (int r = 0; r < 4; ++r) rl[mi][r] = 1.f / lrow[mi][r];
#pragma unroll
  for (int mi = 0; mi < 2; ++mi)
#pragma unroll
    for (int nj = 0; nj < 8; ++nj) {
      const int col = h * 128 + nj * 16 + fr;
#pragma unroll
      for (int r = 0; r < 4; ++r) {
        const int trow = q0 + w * 32 + mi * 16 + fq * 4 + r;
        AO[((long)(b * 512 + trow) << 10) + col] = __float2bfloat16(o[mi][nj][r] * rl[mi][r]);
      }
    }
}

// ---------------- launch ----------------
extern "C" void kernel_launch(void* const* d_in, const int* in_sizes, int n_in,
                              void* d_out, int out_size, void* d_ws, size_t ws_size,
                              hipStream_t stream) {
  const float* xf = (const float*)d_in[0];
  const float* xs = (const float*)d_in[1];
  // weight order in WW: 0=wq1,1=wk1,2=wv1,3=wq2,4=wk2,5=wv2,6=wo1,7=wo2
  const float* w_f[8] = { (const float*)d_in[2], (const float*)d_in[4], (const float*)d_in[6],
                          (const float*)d_in[8], (const float*)d_in[10], (const float*)d_in[12],
                          (const float*)d_in[14], (const float*)d_in[16] };

  bf16* ws = (bf16*)d_ws;
  bf16* XF = ws;                       // 8,388,608 bf16
  bf16* XS = ws + 8388608;             // 8,388,608
  bf16* WW = ws + 16777216;            // 8 x 262,144
  bf16* Qb = ws + 18874368;            // 16,777,216 each
  bf16* Kb = Qb + 16777216;
  bf16* Vb = Kb + 16777216;            // V^T layout (bh, d, t)
  bf16* AO = ws;                       // reuse XF+XS region

  ConvParams cp;
  cp.j[0] = { xf, XF, 2097152, 0 };
  cp.j[1] = { xs, XS, 2097152, 0 };
  for (int i = 0; i < 8; ++i) cp.j[2 + i] = { w_f[i], WW + i * 262144, 65536, 0 };
  convert_kernel<<<dim3(512, 1, 10), 256, 0, stream>>>(cp);

  const float qsc = 0.125f * 1.44269504088896f;   // fold log2(e) so attn uses exp2
  GemmParams gp;
  gp.s[0] = { XF, WW + 0 * 262144, (const float*)d_in[3],  Qb, nullptr, 512, 0,  qsc, 0 };
  gp.s[1] = { XS, WW + 3 * 262144, (const float*)d_in[9],  Qb, nullptr, 512, 64, qsc, 0 };
  gp.s[2] = { XF, WW + 1 * 262144, (const float*)d_in[5],  Kb, nullptr, 512, 0,  1.f, 0 };
  gp.s[3] = { XS, WW + 4 * 262144, (const float*)d_in[11], Kb, nullptr, 512, 64, 1.f, 0 };
  gp.s[4] = { XF, WW + 2 * 262144, (const float*)d_in[7],  Vb, nullptr, 512, 0,  1.f, 2 };
  gp.s[5] = { XS, WW + 5 * 262144, (const float*)d_in[13], Vb, nullptr, 512, 64, 1.f, 2 };
  gemm_kernel<<<dim3(64, 2, 6), 512, 0, stream>>>(gp);

  attn_kernel<<<dim3(1024), 256, 0, stream>>>(Qb, Kb, Vb, AO);

  float* out = (float*)d_out;
  GemmParams op;
  op.s[0] = { AO,       WW + 6 * 262144, (const float*)d_in[15], nullptr, out,           1024, 0, 1.f, 1 };
  op.s[1] = { AO + 512, WW + 7 * 262144, (const float*)d_in[17], nullptr, out + 8388608, 1024, 0, 1.f, 1 };
  op.s[2] = op.s[0]; op.s[3] = op.s[0]; op.s[4] = op.s[0]; op.s[5] = op.s[0];
  gemm_kernel<<<dim3(64, 2, 2), 512, 0, stream>>>(op);
}